// Round 8
// baseline (59.601 us; speedup 1.0000x reference)
//
#include <hip/hip_runtime.h>
#include <hip/hip_fp16.h>
#include <math.h>

#define N_  2
#define C_  128
#define H_  128
#define W_  128
#define G_  4
#define GC_ 32
#define P_  9
#define X1S 132
#define OFS 73

#define DESC_BYTES ((size_t)N_ * H_ * W_ * G_ * P_ * 16)   // 18.9 MB
#define XH_BYTES   ((size_t)N_ * H_ * W_ * C_ * 2)         // 8.4 MB

union HU { __half h; unsigned short u; };
static __device__ __forceinline__ unsigned int f2h(float f) {
    HU x; x.h = __float2half(f); return (unsigned int)x.u;
}
static __device__ __forceinline__ float h2f(unsigned int v) {
    HU x; x.u = (unsigned short)v; return __half2float(x.h);
}
static __device__ __forceinline__ unsigned short f2bf(float f) {
    unsigned int u = __float_as_uint(f);
    u += 0x7FFFu + ((u >> 16) & 1u);
    return (unsigned short)(u >> 16);
}
static __device__ __forceinline__ float bf2f(unsigned short u) {
    return __uint_as_float(((unsigned int)u) << 16);
}

using bf16x8 = __attribute__((ext_vector_type(8))) short;
using f32x4  = __attribute__((ext_vector_type(4))) float;

// ===================== K0: xin fp32 -> fp16 =====================
__global__ __launch_bounds__(256, 8)
void dcn_cvt(const float* __restrict__ xin, __half* __restrict__ xh)
{
    const int i = blockIdx.x * 256 + threadIdx.x;      // 524288 threads x 8 floats
    const float4 a = ((const float4*)xin)[2 * i];
    const float4 b = ((const float4*)xin)[2 * i + 1];
    const __half2 h0 = __floats2half2_rn(a.x, a.y);
    const __half2 h1 = __floats2half2_rn(a.z, a.w);
    const __half2 h2 = __floats2half2_rn(b.x, b.y);
    const __half2 h3 = __floats2half2_rn(b.z, b.w);
    uint4 o;
    o.x = *(const unsigned int*)&h0;
    o.y = *(const unsigned int*)&h1;
    o.z = *(const unsigned int*)&h2;
    o.w = *(const unsigned int*)&h3;
    ((uint4*)xh)[i] = o;
}

// ===================== K1: conv + LN + GELU + MFMA offset GEMM + desc pack =====================
// 1024 blocks x 256 thr (4 waves). Block = 32 px of one row.
// LDS: inb bf16[384][40] (30720) | red (2112) | stat (256) | offwt bf16[72][136] (19584)
//   x1t bf16[32][136] aliases inb[0..8704); offs f32[32][76] aliases inb[16384..26112).
#define K1_RED1_OFF 30720
#define K1_RED2_OFF (30720 + 1056)
#define K1_STAT_OFF (30720 + 2112)
#define K1_OFFW_OFF (30720 + 2112 + 256)
#define K1_OFFS_OFF 16384
#define K1_ARENA    (K1_OFFW_OFF + 19584)

__global__ __launch_bounds__(256, 3)
void dcn_convoffs(const float* __restrict__ inp,   // [N,C,H,W]
                  const float* __restrict__ dww,   // [3,3,1,C]
                  const float* __restrict__ dwb,   // [C]
                  const float* __restrict__ lng,   // [C]
                  const float* __restrict__ lnb,   // [C]
                  const float* __restrict__ offw,  // [72,C]
                  const float* __restrict__ offb,  // [72]
                  uint4* __restrict__ desc)        // [N*H*W, 36]
{
    __shared__ __align__(16) char arena[K1_ARENA];
    unsigned short* inb   = (unsigned short*)arena;                  // [384][40]
    unsigned short* x1t   = (unsigned short*)arena;                  // [32][136] alias
    float*          offs  = (float*)(arena + K1_OFFS_OFF);          // [32][76] alias
    float* red1 = (float*)(arena + K1_RED1_OFF);
    float* red2 = (float*)(arena + K1_RED2_OFF);
    float* stat = (float*)(arena + K1_STAT_OFF);
    unsigned short* offwt = (unsigned short*)(arena + K1_OFFW_OFF); // [72][136]

    const int t   = threadIdx.x;
    const int bid = blockIdx.x;
    const int sw  = ((bid & 7) << 7) | (bid >> 3);   // 1024 = 8 XCD x 128
    const int wq  = sw & 3;
    const int h   = (sw >> 2) & (H_ - 1);
    const int n   = sw >> 9;
    const int w0  = wq * 32;
    const int pixbase = (n * H_ + h) * W_ + w0;

    // ---- stage input tile (bf16) + offw (bf16) ----
    {
        #pragma unroll
        for (int rd = 0; rd < 12; ++rd) {
            const int seg = rd * 32 + (t >> 3);
            const int i   = t & 7;
            const int c   = seg / 3;
            const int r   = seg - c * 3;
            const int hr  = h - 1 + r;
            const int col0 = w0 - 4 + 4 * i;
            float4 v = make_float4(0.f, 0.f, 0.f, 0.f);
            if (hr >= 0 && hr < H_ && col0 >= 0 && col0 <= W_ - 4)
                v = *(const float4*)&inp[(((size_t)n * C_ + c) * H_ + hr) * W_ + col0];
            *(ushort4*)&inb[seg * 40 + 4 * i] =
                make_ushort4(f2bf(v.x), f2bf(v.y), f2bf(v.z), f2bf(v.w));
        }
        #pragma unroll
        for (int rd = 0; rd < 3; ++rd) {
            const int seg = rd * 128 + (t >> 1);
            const int i   = 8 + (t & 1);
            const int c   = seg / 3;
            const int r   = seg - c * 3;
            const int hr  = h - 1 + r;
            const int col0 = w0 - 4 + 4 * i;
            float4 v = make_float4(0.f, 0.f, 0.f, 0.f);
            if (hr >= 0 && hr < H_ && col0 >= 0 && col0 <= W_ - 4)
                v = *(const float4*)&inp[(((size_t)n * C_ + c) * H_ + hr) * W_ + col0];
            *(ushort4*)&inb[seg * 40 + 4 * i] =
                make_ushort4(f2bf(v.x), f2bf(v.y), f2bf(v.z), f2bf(v.w));
        }
        const float4* src = (const float4*)offw;
        #pragma unroll
        for (int k = 0; k < 9; ++k) {
            const int i = t + 256 * k;       // 2304 float4
            const int o = i >> 5;
            const int u = i & 31;
            const float4 v = src[i];
            *(ushort4*)&offwt[o * 136 + u * 4] =
                make_ushort4(f2bf(v.x), f2bf(v.y), f2bf(v.z), f2bf(v.w));
        }
    }
    __syncthreads();

    // ---- conv: thread = (px = t&31, q = t>>5), 16 ch each ----
    const int px = t & 31;
    const int q  = t >> 5;
    float y[16];
    {
        #pragma unroll
        for (int g4 = 0; g4 < 4; ++g4) {
            const int c0 = q * 16 + g4 * 4;
            float4 wv[9];
            #pragma unroll
            for (int k = 0; k < 9; ++k) wv[k] = *(const float4*)&dww[k * C_ + c0];
            const float4 bias = *(const float4*)&dwb[c0];
            #pragma unroll
            for (int ch = 0; ch < 4; ++ch) {
                const int c = c0 + ch;
                float a = ((const float*)&bias)[ch];
                const unsigned short* rowp = &inb[c * 3 * 40];
                #pragma unroll
                for (int r = 0; r < 3; ++r)
                    #pragma unroll
                    for (int dx = 0; dx < 3; ++dx)
                        a = fmaf(bf2f(rowp[r * 40 + px + dx + 3]),
                                 ((const float*)&wv[r * 3 + dx])[ch], a);
                y[g4 * 4 + ch] = a;
            }
        }
        float s1 = 0.f, s2 = 0.f;
        #pragma unroll
        for (int i = 0; i < 16; ++i) { s1 += y[i]; s2 = fmaf(y[i], y[i], s2); }
        red1[q * 33 + px] = s1;
        red2[q * 33 + px] = s2;
    }
    __syncthreads();

    if (t < 32) {
        float s1 = 0.f, s2 = 0.f;
        #pragma unroll
        for (int j = 0; j < 8; ++j) { s1 += red1[j * 33 + t]; s2 += red2[j * 33 + t]; }
        const float mean = s1 * (1.f / 128.f);
        const float var  = s2 * (1.f / 128.f) - mean * mean;
        stat[t]      = mean;
        stat[32 + t] = rsqrtf(var + 1e-6f);
    }
    __syncthreads();

    // ---- LN + GELU -> x1t bf16 (aliases inb; all inb reads done) ----
    {
        const float mean = stat[px];
        const float rstd = stat[32 + px];
        union { unsigned short us[16]; uint4 u4[2]; } o;
        #pragma unroll
        for (int g4 = 0; g4 < 4; ++g4) {
            const int c0 = q * 16 + g4 * 4;
            const float4 lg = *(const float4*)&lng[c0];
            const float4 lb = *(const float4*)&lnb[c0];
            #pragma unroll
            for (int ch = 0; ch < 4; ++ch) {
                float v = (y[g4 * 4 + ch] - mean) * rstd * ((const float*)&lg)[ch]
                          + ((const float*)&lb)[ch];
                v = 0.5f * v * (1.f + erff(v * 0.70710678118654752440f));
                o.us[g4 * 4 + ch] = f2bf(v);
            }
        }
        *(uint4*)&x1t[px * 136 + q * 16]     = o.u4[0];
        *(uint4*)&x1t[px * 136 + q * 16 + 8] = o.u4[1];
    }
    __syncthreads();

    // ---- MFMA offset GEMM: 32px x 72o x K128 ----
    {
        const int lane = t & 63;
        const int wave = t >> 6;
        const int m16  = lane & 15;
        const int kb   = lane >> 4;
        const int mt   = wave & 1;            // m-tile (16 px)
        const int nb   = wave >> 1;           // n-tile base
        bf16x8 afr[4];
        const int apx = mt * 16 + m16;
        #pragma unroll
        for (int st = 0; st < 4; ++st)
            afr[st] = *(const bf16x8*)&x1t[apx * 136 + st * 32 + kb * 8];
        #pragma unroll
        for (int j = 0; j < 3; ++j) {
            const int nt = nb + 2 * j;        // waves 0/1: 0,2,4 ; waves 2/3: 1,3
            if (nt > 4) break;
            const int orow = nt * 16 + m16;
            const bf16x8 b0 = *(const bf16x8*)&offwt[orow * 136 + 0 * 32 + kb * 8];
            const bf16x8 b1 = *(const bf16x8*)&offwt[orow * 136 + 1 * 32 + kb * 8];
            const bf16x8 b2 = *(const bf16x8*)&offwt[orow * 136 + 2 * 32 + kb * 8];
            const bf16x8 b3 = *(const bf16x8*)&offwt[orow * 136 + 3 * 32 + kb * 8];
            const float bias = (orow < 72) ? offb[orow] : 0.f;
            f32x4 acc = {bias, bias, bias, bias};
            acc = __builtin_amdgcn_mfma_f32_16x16x32_bf16(afr[0], b0, acc, 0, 0, 0);
            acc = __builtin_amdgcn_mfma_f32_16x16x32_bf16(afr[1], b1, acc, 0, 0, 0);
            acc = __builtin_amdgcn_mfma_f32_16x16x32_bf16(afr[2], b2, acc, 0, 0, 0);
            acc = __builtin_amdgcn_mfma_f32_16x16x32_bf16(afr[3], b3, acc, 0, 0, 0);
            if (orow < 72) {
                #pragma unroll
                for (int reg = 0; reg < 4; ++reg) {
                    const int pxl = mt * 16 + kb * 4 + reg;
                    offs[pxl * 76 + orow] = acc[reg];
                }
            }
        }
    }
    __syncthreads();

    // ---- descriptor pack: 32 px x 36 taps = 1152 ----
    for (int tap = t; tap < 32 * 36; tap += 256) {
        const int pix = tap / 36;
        const int rem = tap - pix * 36;
        const int g   = rem / 9;
        const int p   = rem - g * 9;
        const float ox = offs[pix * 76 + g * 18 + 2 * p];
        const float oy = offs[pix * 76 + g * 18 + 2 * p + 1];
        const float fy = (float)(h + (p % 3)) + oy;
        const float fx = (float)(w0 + pix + (p / 3)) + ox;
        const float y0f = floorf(fy);
        const float x0f = floorf(fx);
        const float wy = fy - y0f;
        const float wx = fx - x0f;
        const int y0 = (int)y0f;
        const int x0 = (int)x0f;
        const int yc0 = min(max(y0, 1), H_) - 1;
        const int yc1 = min(max(y0 + 1, 1), H_) - 1;
        const int xc0 = min(max(x0, 1), W_) - 1;
        const int xc1 = min(max(x0 + 1, 1), W_) - 1;
        const float a0 = (1.f - wy) * ((y0 >= 1 && y0 <= H_) ? 1.f : 0.f);
        const float a1 = wy * ((y0 + 1 >= 1 && y0 + 1 <= H_) ? 1.f : 0.f);
        const float b0 = (1.f - wx) * ((x0 >= 1 && x0 <= W_) ? 1.f : 0.f);
        const float b1 = wx * ((x0 + 1 >= 1 && x0 + 1 <= W_) ? 1.f : 0.f);
        const unsigned int i00 = (unsigned int)(yc0 * W_ + xc0);
        const unsigned int i01 = (unsigned int)(yc0 * W_ + xc1);
        const unsigned int i10 = (unsigned int)(yc1 * W_ + xc0);
        const unsigned int i11 = (unsigned int)(yc1 * W_ + xc1);
        desc[(size_t)pixbase * 36 + tap] =
            make_uint4(i00 | (i01 << 16),
                       i10 | (i11 << 16),
                       f2h(a0 * b0) | (f2h(a0 * b1) << 16),
                       f2h(a1 * b0) | (f2h(a1 * b1) << 16));
    }
}

// ===================== K2: gather from fp16 x =====================
// 1024 blocks x 512 thr. Block = 32 px. thread = (quad=t&3: 8ch, pair=t>>2: pix*4+g)
__global__ __launch_bounds__(512, 2)
void dcn_gather(const __half* __restrict__ xh,   // [N,H*W,C] fp16
                const uint4* __restrict__ desc,  // [N*H*W, 36]
                float* __restrict__ out)         // [N,C,H,W]
{
    __shared__ __align__(16) float stage[32 * X1S];

    const int t   = threadIdx.x;
    const int bid = blockIdx.x;
    const int sw  = ((bid & 7) << 7) | (bid >> 3);   // 1024 = 8 x 128
    const int wq  = sw & 3;
    const int h   = (sw >> 2) & (H_ - 1);
    const int n   = sw >> 9;
    const int w0  = wq * 32;
    const int pixbase = (n * H_ + h) * W_ + w0;

    {
        const int quad = t & 3;               // 8-ch slot within group
        const int pair = t >> 2;              // 0..127 = pix*4+g
        const int pix  = pair >> 2;
        const int g    = pair & 3;
        const uint4* dp = desc + (size_t)(pixbase + pix) * 36 + g * 9;
        const uint4* xg = (const uint4*)xh + (size_t)n * (H_ * W_ * 16) + g * 4 + quad;

        uint4 d[9];
        #pragma unroll
        for (int p = 0; p < P_; ++p) d[p] = dp[p];

        float a[8];
        #pragma unroll
        for (int e = 0; e < 8; ++e) a[e] = 0.f;

        #pragma unroll
        for (int p = 0; p < P_; ++p) {
            const uint4 v00 = xg[(d[p].x & 0xFFFFu) * 16u];
            const uint4 v01 = xg[(d[p].x >> 16) * 16u];
            const uint4 v10 = xg[(d[p].y & 0xFFFFu) * 16u];
            const uint4 v11 = xg[(d[p].y >> 16) * 16u];
            const float w00 = h2f(d[p].z & 0xFFFFu), w01 = h2f(d[p].z >> 16);
            const float w10 = h2f(d[p].w & 0xFFFFu), w11 = h2f(d[p].w >> 16);
            const __half2* c00 = (const __half2*)&v00;
            const __half2* c01 = (const __half2*)&v01;
            const __half2* c10 = (const __half2*)&v10;
            const __half2* c11 = (const __half2*)&v11;
            #pragma unroll
            for (int u = 0; u < 4; ++u) {
                const float2 f00 = __half22float2(c00[u]);
                const float2 f01 = __half22float2(c01[u]);
                const float2 f10 = __half22float2(c10[u]);
                const float2 f11 = __half22float2(c11[u]);
                a[2*u]   = fmaf(w00, f00.x, a[2*u]);
                a[2*u+1] = fmaf(w00, f00.y, a[2*u+1]);
                a[2*u]   = fmaf(w01, f01.x, a[2*u]);
                a[2*u+1] = fmaf(w01, f01.y, a[2*u+1]);
                a[2*u]   = fmaf(w10, f10.x, a[2*u]);
                a[2*u+1] = fmaf(w10, f10.y, a[2*u+1]);
                a[2*u]   = fmaf(w11, f11.x, a[2*u]);
                a[2*u+1] = fmaf(w11, f11.y, a[2*u+1]);
            }
        }
        float* sp = &stage[pix * X1S + g * GC_ + quad * 8];
        *(float4*)sp       = make_float4(a[0], a[1], a[2], a[3]);
        *(float4*)(sp + 4) = make_float4(a[4], a[5], a[6], a[7]);
    }
    __syncthreads();

    // NCHW write: 32-px contiguous segments
    {
        const int pix = t & 31;
        const int c0  = t >> 5;               // 0..15
        #pragma unroll
        for (int i = 0; i < 8; ++i) {
            const int c = c0 + 16 * i;
            out[(((size_t)n * C_ + c) * H_ + h) * W_ + w0 + pix] = stage[pix * X1S + c];
        }
    }
}

// ===================== fallback: monolithic (fp32) =====================
#define ARENA_BYTES 22336
#define WT  16
__global__ __launch_bounds__(256, 6)
void dcn_fused_mono(const float* __restrict__ inp, const float* __restrict__ xin,
                    const float* __restrict__ dww, const float* __restrict__ dwb,
                    const float* __restrict__ lng, const float* __restrict__ lnb,
                    const float* __restrict__ offw, const float* __restrict__ offb,
                    float* __restrict__ out)
{
    __shared__ __align__(16) char arena[ARENA_BYTES];
    float*  x1     = (float*)arena;
    uint4*  desc4  = (uint4*)(arena + 8448);
    float*  red1   = (float*)(arena + 8448);
    float*  red2   = (float*)(arena + 9472);
    float*  offs   = (float*)(arena + 17664);

    const int t   = threadIdx.x;
    const int bid = blockIdx.x;
    const int sw  = ((bid & 7) << 8) | (bid >> 3);
    const int wt  = sw & 7;
    const int h   = (sw >> 3) & (H_ - 1);
    const int n   = sw >> 10;
    const int w0  = wt * WT;

    {
        const int w = t & 15;
        const int q = t >> 4;
        float s1 = 0.f, s2 = 0.f;
        const int wcb = w0 + w - 1;
        #pragma unroll
        for (int i = 0; i < 8; ++i) {
            const int c = q * 8 + i;
            float acc = dwb[c];
            #pragma unroll
            for (int r = 0; r < 3; ++r) {
                const int hr = h - 1 + r;
                const bool rv = (hr >= 0) && (hr < H_);
                const float* row = inp + (((size_t)n * C_ + c) * H_ + hr) * W_;
                #pragma unroll
                for (int s = 0; s < 3; ++s) {
                    const int wc = wcb + s;
                    const float v = (rv && wc >= 0 && wc < W_) ? row[wc] : 0.f;
                    acc = fmaf(v, dww[(r * 3 + s) * C_ + c], acc);
                }
            }
            x1[w * X1S + c] = acc;
            s1 += acc;
            s2 = fmaf(acc, acc, s2);
        }
        red1[q * 16 + w] = s1;
        red2[q * 16 + w] = s2;
    }
    __syncthreads();
    {
        const int w = t & 15;
        const int q = t >> 4;
        float s1 = 0.f, s2 = 0.f;
        #pragma unroll
        for (int j = 0; j < 16; ++j) { s1 += red1[j * 16 + w]; s2 += red2[j * 16 + w]; }
        const float mean = s1 * (1.f / 128.f);
        const float var  = s2 * (1.f / 128.f) - mean * mean;
        const float rstd = rsqrtf(var + 1e-6f);
        #pragma unroll
        for (int i = 0; i < 8; ++i) {
            const int c = q * 8 + i;
            float v = x1[w * X1S + c];
            v = (v - mean) * rstd * lng[c] + lnb[c];
            v = 0.5f * v * (1.f + erff(v * 0.70710678118654752440f));
            x1[w * X1S + c] = v;
        }
    }
    __syncthreads();
    {
        const int pix  = t & 15;
        const int s    = t >> 4;
        const bool has5 = (s < 8);
        float acc[5];
        #pragma unroll
        for (int j = 0; j < 4; ++j) acc[j] = offb[s * 4 + j];
        acc[4] = has5 ? offb[64 + s] : 0.f;
        #pragma unroll 1
        for (int cb = 0; cb < C_; cb += 8) {
            const float4 xa = *(const float4*)&x1[pix * X1S + cb];
            const float4 xb = *(const float4*)&x1[pix * X1S + cb + 4];
            #pragma unroll
            for (int j = 0; j < 4; ++j) {
                const int o = s * 4 + j;
                const float4 wa = *(const float4*)&offw[o * C_ + cb];
                const float4 wb = *(const float4*)&offw[o * C_ + cb + 4];
                acc[j] = fmaf(xa.x, wa.x, acc[j]);
                acc[j] = fmaf(xa.y, wa.y, acc[j]);
                acc[j] = fmaf(xa.z, wa.z, acc[j]);
                acc[j] = fmaf(xa.w, wa.w, acc[j]);
                acc[j] = fmaf(xb.x, wb.x, acc[j]);
                acc[j] = fmaf(xb.y, wb.y, acc[j]);
                acc[j] = fmaf(xb.z, wb.z, acc[j]);
                acc[j] = fmaf(xb.w, wb.w, acc[j]);
            }
            if (has5) {
                const int o = 64 + s;
                const float4 wa = *(const float4*)&offw[o * C_ + cb];
                const float4 wb = *(const float4*)&offw[o * C_ + cb + 4];
                acc[4] = fmaf(xa.x, wa.x, acc[4]);
                acc[4] = fmaf(xa.y, wa.y, acc[4]);
                acc[4] = fmaf(xa.z, wa.z, acc[4]);
                acc[4] = fmaf(xa.w, wa.w, acc[4]);
                acc[4] = fmaf(xb.x, wb.x, acc[4]);
                acc[4] = fmaf(xb.y, wb.y, acc[4]);
                acc[4] = fmaf(xb.z, wb.z, acc[4]);
                acc[4] = fmaf(xb.w, wb.w, acc[4]);
            }
        }
        #pragma unroll
        for (int j = 0; j < 4; ++j) offs[pix * OFS + s * 4 + j] = acc[j];
        if (has5) offs[pix * OFS + 64 + s] = acc[4];
    }
    __syncthreads();
    {
        for (int tap = t; tap < WT * G_ * P_; tap += 256) {
            const int pg  = tap / 9;
            const int p   = tap - pg * 9;
            const int pix = pg >> 2;
            const int g   = pg & 3;
            const float ox = offs[pix * OFS + g * 18 + 2 * p];
            const float oy = offs[pix * OFS + g * 18 + 2 * p + 1];
            const float fy = (float)(h + (p % 3)) + oy;
            const float fx = (float)(w0 + pix + (p / 3)) + ox;
            const float y0f = floorf(fy);
            const float x0f = floorf(fx);
            const float wy = fy - y0f;
            const float wx = fx - x0f;
            const int y0 = (int)y0f;
            const int x0 = (int)x0f;
            const int yc0 = min(max(y0, 1), H_) - 1;
            const int yc1 = min(max(y0 + 1, 1), H_) - 1;
            const int xc0 = min(max(x0, 1), W_) - 1;
            const int xc1 = min(max(x0 + 1, 1), W_) - 1;
            const float a0 = (1.f - wy) * ((y0 >= 1 && y0 <= H_) ? 1.f : 0.f);
            const float a1 = wy * ((y0 + 1 >= 1 && y0 + 1 <= H_) ? 1.f : 0.f);
            const float b0 = (1.f - wx) * ((x0 >= 1 && x0 <= W_) ? 1.f : 0.f);
            const float b1 = wx * ((x0 + 1 >= 1 && x0 + 1 <= W_) ? 1.f : 0.f);
            const unsigned int i00 = (unsigned int)(yc0 * W_ + xc0);
            const unsigned int i01 = (unsigned int)(yc0 * W_ + xc1);
            const unsigned int i10 = (unsigned int)(yc1 * W_ + xc0);
            const unsigned int i11 = (unsigned int)(yc1 * W_ + xc1);
            desc4[tap] = make_uint4(i00 | (i01 << 16),
                                    i10 | (i11 << 16),
                                    f2h(a0 * b0) | (f2h(a0 * b1) << 16),
                                    f2h(a1 * b0) | (f2h(a1 * b1) << 16));
        }
    }
    __syncthreads();
    {
        const int k    = t & 15;
        const int slot = t >> 4;
        const float2* xb2 = (const float2*)xin + (size_t)n * (H_ * W_ * C_ / 2) + k;
        float2* st = (float2*)x1;
        #pragma unroll 1
        for (int it = 0; it < 2; ++it) {
            const int pairA = it * 32 + slot;
            const int pairB = pairA + 16;
            const int pixA = pairA >> 2, gA = pairA & 3;
            const int pixB = pairB >> 2, gB = pairB & 3;
            const float2* xgA = xb2 + gA * (GC_ / 2);
            const float2* xgB = xb2 + gB * (GC_ / 2);
            const uint4* dAp = desc4 + pairA * 9;
            const uint4* dBp = desc4 + pairB * 9;
            float aAx = 0.f, aAy = 0.f, aBx = 0.f, aBy = 0.f;
            #pragma unroll
            for (int p = 0; p < P_; ++p) {
                const uint4 da = dAp[p];
                const uint4 db = dBp[p];
                const float2 vA00 = xgA[(da.x & 0xFFFFu) * 64u];
                const float2 vA01 = xgA[(da.x >> 16) * 64u];
                const float2 vA10 = xgA[(da.y & 0xFFFFu) * 64u];
                const float2 vA11 = xgA[(da.y >> 16) * 64u];
                const float2 vB00 = xgB[(db.x & 0xFFFFu) * 64u];
                const float2 vB01 = xgB[(db.x >> 16) * 64u];
                const float2 vB10 = xgB[(db.y & 0xFFFFu) * 64u];
                const float2 vB11 = xgB[(db.y >> 16) * 64u];
                const float wA00 = h2f(da.z & 0xFFFFu), wA01 = h2f(da.z >> 16);
                const float wA10 = h2f(da.w & 0xFFFFu), wA11 = h2f(da.w >> 16);
                const float wB00 = h2f(db.z & 0xFFFFu), wB01 = h2f(db.z >> 16);
                const float wB10 = h2f(db.w & 0xFFFFu), wB11 = h2f(db.w >> 16);
                aAx = fmaf(wA00, vA00.x, aAx); aAy = fmaf(wA00, vA00.y, aAy);
                aAx = fmaf(wA01, vA01.x, aAx); aAy = fmaf(wA01, vA01.y, aAy);
                aAx = fmaf(wA10, vA10.x, aAx); aAy = fmaf(wA10, vA10.y, aAy);
                aAx = fmaf(wA11, vA11.x, aAx); aAy = fmaf(wA11, vA11.y, aAy);
                aBx = fmaf(wB00, vB00.x, aBx); aBy = fmaf(wB00, vB00.y, aBy);
                aBx = fmaf(wB01, vB01.x, aBx); aBy = fmaf(wB01, vB01.y, aBy);
                aBx = fmaf(wB10, vB10.x, aBx); aBy = fmaf(wB10, vB10.y, aBy);
                aBx = fmaf(wB11, vB11.x, aBx); aBy = fmaf(wB11, vB11.y, aBy);
            }
            st[pixA * (X1S / 2) + gA * (GC_ / 2) + k] = make_float2(aAx, aAy);
            st[pixB * (X1S / 2) + gB * (GC_ / 2) + k] = make_float2(aBx, aBy);
        }
    }
    __syncthreads();
    {
        const int pix = t & 15;
        const int cq  = t >> 4;
        #pragma unroll
        for (int i = 0; i < 8; ++i) {
            const int c = cq * 8 + i;
            out[(((size_t)n * C_ + c) * H_ + h) * W_ + w0 + pix] = x1[pix * X1S + c];
        }
    }
}

extern "C" void kernel_launch(void* const* d_in, const int* in_sizes, int n_in,
                              void* d_out, int out_size, void* d_ws, size_t ws_size,
                              hipStream_t stream) {
    const float* inp  = (const float*)d_in[0];
    const float* xin  = (const float*)d_in[1];
    const float* dww  = (const float*)d_in[2];
    const float* dwb  = (const float*)d_in[3];
    const float* lng  = (const float*)d_in[4];
    const float* lnb  = (const float*)d_in[5];
    const float* offw = (const float*)d_in[6];
    const float* offb = (const float*)d_in[7];
    float* outp = (float*)d_out;

    if (ws_size >= DESC_BYTES + XH_BYTES) {
        uint4*  desc = (uint4*)d_ws;
        __half* xh   = (__half*)((char*)d_ws + DESC_BYTES);
        dcn_cvt<<<dim3(2048), dim3(256), 0, stream>>>(xin, xh);
        dcn_convoffs<<<dim3(1024), dim3(256), 0, stream>>>(
            inp, dww, dwb, lng, lnb, offw, offb, desc);
        dcn_gather<<<dim3(1024), dim3(512), 0, stream>>>(xh, desc, outp);
    } else {
        dcn_fused_mono<<<dim3(N_ * H_ * (W_ / WT)), dim3(256), 0, stream>>>(
            inp, xin, dww, dwb, lng, lnb, offw, offb, outp);
    }
}

// Round 9
// 58.192 us; speedup vs baseline: 1.0242x; 1.0242x over previous
//
#include <hip/hip_runtime.h>
#include <hip/hip_fp16.h>
#include <math.h>

#define N_  2
#define C_  128
#define H_  128
#define W_  128
#define G_  4
#define GC_ 32
#define P_  9
#define WT  16
#define X1S 132
#define OFS 73

#define DESC_BYTES ((size_t)N_ * H_ * W_ * G_ * P_ * 16)   // 18.9 MB

union HU { __half h; unsigned short u; };
static __device__ __forceinline__ unsigned int f2h(float f) {
    HU x; x.h = __float2half(f); return (unsigned int)x.u;
}
static __device__ __forceinline__ float h2f(unsigned int v) {
    HU x; x.u = (unsigned short)v; return __half2float(x.h);
}
static __device__ __forceinline__ unsigned short f2bf(float f) {
    unsigned int u = __float_as_uint(f);
    u += 0x7FFFu + ((u >> 16) & 1u);
    return (unsigned short)(u >> 16);
}
static __device__ __forceinline__ float bflo(unsigned int u) {   // low bf16 of u32
    return __uint_as_float(u << 16);
}
static __device__ __forceinline__ float bfhi(unsigned int u) {   // high bf16 of u32
    return __uint_as_float(u & 0xFFFF0000u);
}

using bf16x8 = __attribute__((ext_vector_type(8))) short;
using f32x4  = __attribute__((ext_vector_type(4))) float;

// ===================== K1: conv + LN + GELU + MFMA offset GEMM + desc pack =====================
// 1024 blocks x 256 thr (4 waves). Block = 32 px of one row.
// LDS arena:
//   [0,     33792)  inb bf16[384 segs][44]  (conv input staging)
//       x1t  bf16[32][136] aliases [0, 8704)        (post-conv)
//       stat f32[64]       aliases [16384, 16640)   (post-conv)
//       offs f32[32][76]   aliases [16384, 26112)   (MFMA out; stat dead by then)
//   [33792, 34848)  red1/red2 f32[4][33] x2
//   [34848, 54432)  offwt bf16[72][136]
#define K1_RED1  33792
#define K1_RED2  (33792 + 528)
#define K1_STAT  16384
#define K1_OFFS  16384
#define K1_OFFW  34848
#define K1_ARENA (34848 + 19584)     // 54432 -> 3 blocks/CU

__global__ __launch_bounds__(256, 3)
void dcn_convoffs(const float* __restrict__ inp,   // [N,C,H,W]
                  const float* __restrict__ dww,   // [3,3,1,C]
                  const float* __restrict__ dwb,   // [C]
                  const float* __restrict__ lng,   // [C]
                  const float* __restrict__ lnb,   // [C]
                  const float* __restrict__ offw,  // [72,C]
                  const float* __restrict__ offb,  // [72]
                  uint4* __restrict__ desc)        // [N*H*W, 36]
{
    __shared__ __align__(16) char arena[K1_ARENA];
    unsigned short* inb   = (unsigned short*)arena;               // [384][44]
    unsigned short* x1t   = (unsigned short*)arena;               // [32][136] alias
    float*          stat  = (float*)(arena + K1_STAT);            // [64] alias
    float*          offs  = (float*)(arena + K1_OFFS);            // [32][76] alias
    float* red1 = (float*)(arena + K1_RED1);                      // [4][33]
    float* red2 = (float*)(arena + K1_RED2);
    unsigned short* offwt = (unsigned short*)(arena + K1_OFFW);   // [72][136]

    const int t   = threadIdx.x;
    const int bid = blockIdx.x;
    const int sw  = ((bid & 7) << 7) | (bid >> 3);   // 1024 = 8 XCD x 128
    const int wq  = sw & 3;
    const int h   = (sw >> 2) & (H_ - 1);
    const int n   = sw >> 9;
    const int w0  = wq * 32;
    const int pixbase = (n * H_ + h) * W_ + w0;

    // ---- stage input tile (bf16, cols w0-4..w0+35) + offw (bf16) ----
    {
        #pragma unroll
        for (int rd = 0; rd < 12; ++rd) {
            const int seg = rd * 32 + (t >> 3);
            const int i   = t & 7;
            const int c   = seg / 3;
            const int r   = seg - c * 3;
            const int hr  = h - 1 + r;
            const int col0 = w0 - 4 + 4 * i;
            float4 v = make_float4(0.f, 0.f, 0.f, 0.f);
            if (hr >= 0 && hr < H_ && col0 >= 0 && col0 <= W_ - 4)
                v = *(const float4*)&inp[(((size_t)n * C_ + c) * H_ + hr) * W_ + col0];
            *(ushort4*)&inb[seg * 44 + 4 * i] =
                make_ushort4(f2bf(v.x), f2bf(v.y), f2bf(v.z), f2bf(v.w));
        }
        #pragma unroll
        for (int rd = 0; rd < 3; ++rd) {
            const int seg = rd * 128 + (t >> 1);
            const int i   = 8 + (t & 1);
            const int c   = seg / 3;
            const int r   = seg - c * 3;
            const int hr  = h - 1 + r;
            const int col0 = w0 - 4 + 4 * i;
            float4 v = make_float4(0.f, 0.f, 0.f, 0.f);
            if (hr >= 0 && hr < H_ && col0 >= 0 && col0 <= W_ - 4)
                v = *(const float4*)&inp[(((size_t)n * C_ + c) * H_ + hr) * W_ + col0];
            *(ushort4*)&inb[seg * 44 + 4 * i] =
                make_ushort4(f2bf(v.x), f2bf(v.y), f2bf(v.z), f2bf(v.w));
        }
        const float4* src = (const float4*)offw;
        #pragma unroll
        for (int k = 0; k < 9; ++k) {
            const int i = t + 256 * k;       // 2304 float4
            const int o = i >> 5;
            const int u = i & 31;
            const float4 v = src[i];
            *(ushort4*)&offwt[o * 136 + u * 4] =
                make_ushort4(f2bf(v.x), f2bf(v.y), f2bf(v.z), f2bf(v.w));
        }
    }
    __syncthreads();

    // ---- conv: thread = (pq = t&7 -> 4 px, cg = t>>3 -> 4 ch) ----
    const int pq = t & 7;
    const int cg = t >> 3;
    const int c0 = cg * 4;
    float acc[4][4];                         // [ch][j]
    {
        const float4 bias = *(const float4*)&dwb[c0];
        #pragma unroll
        for (int ch = 0; ch < 4; ++ch)
            #pragma unroll
            for (int j = 0; j < 4; ++j) acc[ch][j] = ((const float*)&bias)[ch];

        #pragma unroll
        for (int r = 0; r < 3; ++r) {
            const float4 wd0 = *(const float4*)&dww[(r * 3 + 0) * C_ + c0];
            const float4 wd1 = *(const float4*)&dww[(r * 3 + 1) * C_ + c0];
            const float4 wd2 = *(const float4*)&dww[(r * 3 + 2) * C_ + c0];
            #pragma unroll
            for (int ch = 0; ch < 4; ++ch) {
                const int seg = (c0 + ch) * 3 + r;
                const unsigned short* rp = &inb[seg * 44 + 4 * pq];
                const uint2 a = *(const uint2*)rp;        // s0..s3
                const uint2 b = *(const uint2*)(rp + 4);  // s4..s7
                const unsigned int s8 = rp[8];
                // window values v[k] = s[k], k = 3..8 (px j uses v[j+3+dx])
                const float v3 = bfhi(a.y);
                const float v4 = bflo(b.x);
                const float v5 = bfhi(b.x);
                const float v6 = bflo(b.y);
                const float v7 = bfhi(b.y);
                const float v8 = bflo(s8);
                const float k0 = ((const float*)&wd0)[ch];
                const float k1 = ((const float*)&wd1)[ch];
                const float k2 = ((const float*)&wd2)[ch];
                acc[ch][0] = fmaf(v3, k0, acc[ch][0]);
                acc[ch][0] = fmaf(v4, k1, acc[ch][0]);
                acc[ch][0] = fmaf(v5, k2, acc[ch][0]);
                acc[ch][1] = fmaf(v4, k0, acc[ch][1]);
                acc[ch][1] = fmaf(v5, k1, acc[ch][1]);
                acc[ch][1] = fmaf(v6, k2, acc[ch][1]);
                acc[ch][2] = fmaf(v5, k0, acc[ch][2]);
                acc[ch][2] = fmaf(v6, k1, acc[ch][2]);
                acc[ch][2] = fmaf(v7, k2, acc[ch][2]);
                acc[ch][3] = fmaf(v6, k0, acc[ch][3]);
                acc[ch][3] = fmaf(v7, k1, acc[ch][3]);
                acc[ch][3] = fmaf(v8, k2, acc[ch][3]);
            }
        }
    }

    // ---- LN partials: per px over own 4 ch, then shuffle-reduce over 8 cg/wave ----
    {
        float s1[4], s2[4];
        #pragma unroll
        for (int j = 0; j < 4; ++j) {
            s1[j] = acc[0][j] + acc[1][j] + acc[2][j] + acc[3][j];
            float q = acc[0][j] * acc[0][j];
            q = fmaf(acc[1][j], acc[1][j], q);
            q = fmaf(acc[2][j], acc[2][j], q);
            q = fmaf(acc[3][j], acc[3][j], q);
            s2[j] = q;
        }
        #pragma unroll
        for (int m = 8; m <= 32; m <<= 1) {
            #pragma unroll
            for (int j = 0; j < 4; ++j) {
                s1[j] += __shfl_xor(s1[j], m);
                s2[j] += __shfl_xor(s2[j], m);
            }
        }
        const int lane = t & 63;
        const int wave = t >> 6;
        if ((lane >> 3) == 0) {              // one lane per (wave, pq)
            #pragma unroll
            for (int j = 0; j < 4; ++j) {
                red1[wave * 33 + 4 * pq + j] = s1[j];
                red2[wave * 33 + 4 * pq + j] = s2[j];
            }
        }
    }
    __syncthreads();

    if (t < 32) {
        float s1 = 0.f, s2 = 0.f;
        #pragma unroll
        for (int w = 0; w < 4; ++w) { s1 += red1[w * 33 + t]; s2 += red2[w * 33 + t]; }
        const float mean = s1 * (1.f / 128.f);
        const float var  = s2 * (1.f / 128.f) - mean * mean;
        stat[t]      = mean;
        stat[32 + t] = rsqrtf(var + 1e-6f);
    }
    __syncthreads();

    // ---- LN + GELU -> x1t bf16 ----
    {
        const float4 lg = *(const float4*)&lng[c0];
        const float4 lb = *(const float4*)&lnb[c0];
        #pragma unroll
        for (int j = 0; j < 4; ++j) {
            const int px = 4 * pq + j;
            const float mean = stat[px];
            const float rstd = stat[32 + px];
            ushort4 o;
            unsigned short* op = (unsigned short*)&o;
            #pragma unroll
            for (int ch = 0; ch < 4; ++ch) {
                float v = (acc[ch][j] - mean) * rstd * ((const float*)&lg)[ch]
                          + ((const float*)&lb)[ch];
                v = 0.5f * v * (1.f + erff(v * 0.70710678118654752440f));
                op[ch] = f2bf(v);
            }
            *(ushort4*)&x1t[px * 136 + c0] = o;
        }
    }
    __syncthreads();

    // ---- MFMA offset GEMM: 32px x 72o x K128 ----
    {
        const int lane = t & 63;
        const int wave = t >> 6;
        const int m16  = lane & 15;
        const int kb   = lane >> 4;
        const int mt   = wave & 1;
        const int nb   = wave >> 1;
        bf16x8 afr[4];
        const int apx = mt * 16 + m16;
        #pragma unroll
        for (int st = 0; st < 4; ++st)
            afr[st] = *(const bf16x8*)&x1t[apx * 136 + st * 32 + kb * 8];
        __syncthreads();                     // all afr loaded before offs (alias region) writes
        #pragma unroll
        for (int j = 0; j < 3; ++j) {
            const int nt = nb + 2 * j;       // waves 0/1: 0,2,4 ; waves 2/3: 1,3
            if (nt > 4) break;
            const int orow = nt * 16 + m16;
            const bf16x8 b0 = *(const bf16x8*)&offwt[orow * 136 + 0 * 32 + kb * 8];
            const bf16x8 b1 = *(const bf16x8*)&offwt[orow * 136 + 1 * 32 + kb * 8];
            const bf16x8 b2 = *(const bf16x8*)&offwt[orow * 136 + 2 * 32 + kb * 8];
            const bf16x8 b3 = *(const bf16x8*)&offwt[orow * 136 + 3 * 32 + kb * 8];
            const float bias = (orow < 72) ? offb[orow] : 0.f;
            f32x4 a4 = {bias, bias, bias, bias};
            a4 = __builtin_amdgcn_mfma_f32_16x16x32_bf16(afr[0], b0, a4, 0, 0, 0);
            a4 = __builtin_amdgcn_mfma_f32_16x16x32_bf16(afr[1], b1, a4, 0, 0, 0);
            a4 = __builtin_amdgcn_mfma_f32_16x16x32_bf16(afr[2], b2, a4, 0, 0, 0);
            a4 = __builtin_amdgcn_mfma_f32_16x16x32_bf16(afr[3], b3, a4, 0, 0, 0);
            if (orow < 72) {
                #pragma unroll
                for (int reg = 0; reg < 4; ++reg) {
                    const int pxl = mt * 16 + kb * 4 + reg;
                    offs[pxl * 76 + orow] = a4[reg];
                }
            }
        }
    }
    __syncthreads();

    // ---- descriptor pack: 32 px x 36 taps = 1152 ----
    for (int tap = t; tap < 32 * 36; tap += 256) {
        const int pix = tap / 36;
        const int rem = tap - pix * 36;
        const int g   = rem / 9;
        const int p   = rem - g * 9;
        const float ox = offs[pix * 76 + g * 18 + 2 * p];
        const float oy = offs[pix * 76 + g * 18 + 2 * p + 1];
        const float fy = (float)(h + (p % 3)) + oy;
        const float fx = (float)(w0 + pix + (p / 3)) + ox;
        const float y0f = floorf(fy);
        const float x0f = floorf(fx);
        const float wy = fy - y0f;
        const float wx = fx - x0f;
        const int y0 = (int)y0f;
        const int x0 = (int)x0f;
        const int yc0 = min(max(y0, 1), H_) - 1;
        const int yc1 = min(max(y0 + 1, 1), H_) - 1;
        const int xc0 = min(max(x0, 1), W_) - 1;
        const int xc1 = min(max(x0 + 1, 1), W_) - 1;
        const float a0 = (1.f - wy) * ((y0 >= 1 && y0 <= H_) ? 1.f : 0.f);
        const float a1 = wy * ((y0 + 1 >= 1 && y0 + 1 <= H_) ? 1.f : 0.f);
        const float b0 = (1.f - wx) * ((x0 >= 1 && x0 <= W_) ? 1.f : 0.f);
        const float b1 = wx * ((x0 + 1 >= 1 && x0 + 1 <= W_) ? 1.f : 0.f);
        const unsigned int i00 = (unsigned int)(yc0 * W_ + xc0);
        const unsigned int i01 = (unsigned int)(yc0 * W_ + xc1);
        const unsigned int i10 = (unsigned int)(yc1 * W_ + xc0);
        const unsigned int i11 = (unsigned int)(yc1 * W_ + xc1);
        desc[(size_t)pixbase * 36 + tap] =
            make_uint4(i00 | (i01 << 16),
                       i10 | (i11 << 16),
                       f2h(a0 * b0) | (f2h(a0 * b1) << 16),
                       f2h(a1 * b0) | (f2h(a1 * b1) << 16));
    }
}

// ===================== K2: pure gather (fp32, R7 known-good) =====================
__global__ __launch_bounds__(512, 4)
void dcn_gather(const float* __restrict__ xin,   // [N,H,W,C]
                const uint4* __restrict__ desc,  // [N*H*W, 36]
                float* __restrict__ out)         // [N,C,H,W]
{
    __shared__ __align__(16) float stage[WT * X1S];

    const int t   = threadIdx.x;
    const int bid = blockIdx.x;
    const int sw  = ((bid & 7) << 8) | (bid >> 3);
    const int wt  = sw & 7;
    const int h   = (sw >> 3) & (H_ - 1);
    const int n   = sw >> 10;
    const int w0  = wt * WT;
    const int pixbase = (n * H_ + h) * W_ + w0;

    {
        const int k   = t & 7;
        const int pl  = t >> 3;
        const int pix = pl >> 2;
        const int g   = pl & 3;
        const uint4* dp = desc + (size_t)(pixbase + pix) * 36 + g * 9;
        const float4* xg = (const float4*)xin + (size_t)n * (H_ * W_ * (C_ / 4)) + g * (GC_ / 4) + k;

        uint4 d[9];
        #pragma unroll
        for (int p = 0; p < P_; ++p) d[p] = dp[p];

        float4 acc = make_float4(0.f, 0.f, 0.f, 0.f);
        #pragma unroll
        for (int p = 0; p < P_; ++p) {
            const float4 v00 = xg[(d[p].x & 0xFFFFu) * 32u];
            const float4 v01 = xg[(d[p].x >> 16) * 32u];
            const float4 v10 = xg[(d[p].y & 0xFFFFu) * 32u];
            const float4 v11 = xg[(d[p].y >> 16) * 32u];
            const float w00 = h2f(d[p].z & 0xFFFFu), w01 = h2f(d[p].z >> 16);
            const float w10 = h2f(d[p].w & 0xFFFFu), w11 = h2f(d[p].w >> 16);
            acc.x = fmaf(w00, v00.x, acc.x);
            acc.y = fmaf(w00, v00.y, acc.y);
            acc.z = fmaf(w00, v00.z, acc.z);
            acc.w = fmaf(w00, v00.w, acc.w);
            acc.x = fmaf(w01, v01.x, acc.x);
            acc.y = fmaf(w01, v01.y, acc.y);
            acc.z = fmaf(w01, v01.z, acc.z);
            acc.w = fmaf(w01, v01.w, acc.w);
            acc.x = fmaf(w10, v10.x, acc.x);
            acc.y = fmaf(w10, v10.y, acc.y);
            acc.z = fmaf(w10, v10.z, acc.z);
            acc.w = fmaf(w10, v10.w, acc.w);
            acc.x = fmaf(w11, v11.x, acc.x);
            acc.y = fmaf(w11, v11.y, acc.y);
            acc.z = fmaf(w11, v11.z, acc.z);
            acc.w = fmaf(w11, v11.w, acc.w);
        }
        *(float4*)&stage[pix * X1S + g * GC_ + k * 4] = acc;
    }
    __syncthreads();
    {
        const int pix = t & 15;
        const int c0  = t >> 4;
        #pragma unroll
        for (int i = 0; i < 4; ++i) {
            const int c = c0 + 32 * i;
            out[(((size_t)n * C_ + c) * H_ + h) * W_ + w0 + pix] = stage[pix * X1S + c];
        }
    }
}

// ===================== fallback: monolithic (fp32) =====================
#define ARENA_BYTES 22336
__global__ __launch_bounds__(256, 6)
void dcn_fused_mono(const float* __restrict__ inp, const float* __restrict__ xin,
                    const float* __restrict__ dww, const float* __restrict__ dwb,
                    const float* __restrict__ lng, const float* __restrict__ lnb,
                    const float* __restrict__ offw, const float* __restrict__ offb,
                    float* __restrict__ out)
{
    __shared__ __align__(16) char arena[ARENA_BYTES];
    float*  x1     = (float*)arena;
    uint4*  desc4  = (uint4*)(arena + 8448);
    float*  red1   = (float*)(arena + 8448);
    float*  red2   = (float*)(arena + 9472);
    float*  offs   = (float*)(arena + 17664);

    const int t   = threadIdx.x;
    const int bid = blockIdx.x;
    const int sw  = ((bid & 7) << 8) | (bid >> 3);
    const int wt  = sw & 7;
    const int h   = (sw >> 3) & (H_ - 1);
    const int n   = sw >> 10;
    const int w0  = wt * WT;

    {
        const int w = t & 15;
        const int q = t >> 4;
        float s1 = 0.f, s2 = 0.f;
        const int wcb = w0 + w - 1;
        #pragma unroll
        for (int i = 0; i < 8; ++i) {
            const int c = q * 8 + i;
            float acc = dwb[c];
            #pragma unroll
            for (int r = 0; r < 3; ++r) {
                const int hr = h - 1 + r;
                const bool rv = (hr >= 0) && (hr < H_);
                const float* row = inp + (((size_t)n * C_ + c) * H_ + hr) * W_;
                #pragma unroll
                for (int s = 0; s < 3; ++s) {
                    const int wc = wcb + s;
                    const float v = (rv && wc >= 0 && wc < W_) ? row[wc] : 0.f;
                    acc = fmaf(v, dww[(r * 3 + s) * C_ + c], acc);
                }
            }
            x1[w * X1S + c] = acc;
            s1 += acc;
            s2 = fmaf(acc, acc, s2);
        }
        red1[q * 16 + w] = s1;
        red2[q * 16 + w] = s2;
    }
    __syncthreads();
    {
        const int w = t & 15;
        const int q = t >> 4;
        float s1 = 0.f, s2 = 0.f;
        #pragma unroll
        for (int j = 0; j < 16; ++j) { s1 += red1[j * 16 + w]; s2 += red2[j * 16 + w]; }
        const float mean = s1 * (1.f / 128.f);
        const float var  = s2 * (1.f / 128.f) - mean * mean;
        const float rstd = rsqrtf(var + 1e-6f);
        #pragma unroll
        for (int i = 0; i < 8; ++i) {
            const int c = q * 8 + i;
            float v = x1[w * X1S + c];
            v = (v - mean) * rstd * lng[c] + lnb[c];
            v = 0.5f * v * (1.f + erff(v * 0.70710678118654752440f));
            x1[w * X1S + c] = v;
        }
    }
    __syncthreads();
    {
        const int pix  = t & 15;
        const int s    = t >> 4;
        const bool has5 = (s < 8);
        float acc[5];
        #pragma unroll
        for (int j = 0; j < 4; ++j) acc[j] = offb[s * 4 + j];
        acc[4] = has5 ? offb[64 + s] : 0.f;
        #pragma unroll 1
        for (int cb = 0; cb < C_; cb += 8) {
            const float4 xa = *(const float4*)&x1[pix * X1S + cb];
            const float4 xb = *(const float4*)&x1[pix * X1S + cb + 4];
            #pragma unroll
            for (int j = 0; j < 4; ++j) {
                const int o = s * 4 + j;
                const float4 wa = *(const float4*)&offw[o * C_ + cb];
                const float4 wb = *(const float4*)&offw[o * C_ + cb + 4];
                acc[j] = fmaf(xa.x, wa.x, acc[j]);
                acc[j] = fmaf(xa.y, wa.y, acc[j]);
                acc[j] = fmaf(xa.z, wa.z, acc[j]);
                acc[j] = fmaf(xa.w, wa.w, acc[j]);
                acc[j] = fmaf(xb.x, wb.x, acc[j]);
                acc[j] = fmaf(xb.y, wb.y, acc[j]);
                acc[j] = fmaf(xb.z, wb.z, acc[j]);
                acc[j] = fmaf(xb.w, wb.w, acc[j]);
            }
            if (has5) {
                const int o = 64 + s;
                const float4 wa = *(const float4*)&offw[o * C_ + cb];
                const float4 wb = *(const float4*)&offw[o * C_ + cb + 4];
                acc[4] = fmaf(xa.x, wa.x, acc[4]);
                acc[4] = fmaf(xa.y, wa.y, acc[4]);
                acc[4] = fmaf(xa.z, wa.z, acc[4]);
                acc[4] = fmaf(xa.w, wa.w, acc[4]);
                acc[4] = fmaf(xb.x, wb.x, acc[4]);
                acc[4] = fmaf(xb.y, wb.y, acc[4]);
                acc[4] = fmaf(xb.z, wb.z, acc[4]);
                acc[4] = fmaf(xb.w, wb.w, acc[4]);
            }
        }
        #pragma unroll
        for (int j = 0; j < 4; ++j) offs[pix * OFS + s * 4 + j] = acc[j];
        if (has5) offs[pix * OFS + 64 + s] = acc[4];
    }
    __syncthreads();
    {
        for (int tap = t; tap < WT * G_ * P_; tap += 256) {
            const int pg  = tap / 9;
            const int p   = tap - pg * 9;
            const int pix = pg >> 2;
            const int g   = pg & 3;
            const float ox = offs[pix * OFS + g * 18 + 2 * p];
            const float oy = offs[pix * OFS + g * 18 + 2 * p + 1];
            const float fy = (float)(h + (p % 3)) + oy;
            const float fx = (float)(w0 + pix + (p / 3)) + ox;
            const float y0f = floorf(fy);
            const float x0f = floorf(fx);
            const float wy = fy - y0f;
            const float wx = fx - x0f;
            const int y0 = (int)y0f;
            const int x0 = (int)x0f;
            const int yc0 = min(max(y0, 1), H_) - 1;
            const int yc1 = min(max(y0 + 1, 1), H_) - 1;
            const int xc0 = min(max(x0, 1), W_) - 1;
            const int xc1 = min(max(x0 + 1, 1), W_) - 1;
            const float a0 = (1.f - wy) * ((y0 >= 1 && y0 <= H_) ? 1.f : 0.f);
            const float a1 = wy * ((y0 + 1 >= 1 && y0 + 1 <= H_) ? 1.f : 0.f);
            const float b0 = (1.f - wx) * ((x0 >= 1 && x0 <= W_) ? 1.f : 0.f);
            const float b1 = wx * ((x0 + 1 >= 1 && x0 + 1 <= W_) ? 1.f : 0.f);
            const unsigned int i00 = (unsigned int)(yc0 * W_ + xc0);
            const unsigned int i01 = (unsigned int)(yc0 * W_ + xc1);
            const unsigned int i10 = (unsigned int)(yc1 * W_ + xc0);
            const unsigned int i11 = (unsigned int)(yc1 * W_ + xc1);
            desc4[tap] = make_uint4(i00 | (i01 << 16),
                                    i10 | (i11 << 16),
                                    f2h(a0 * b0) | (f2h(a0 * b1) << 16),
                                    f2h(a1 * b0) | (f2h(a1 * b1) << 16));
        }
    }
    __syncthreads();
    {
        const int k    = t & 15;
        const int slot = t >> 4;
        const float2* xb2 = (const float2*)xin + (size_t)n * (H_ * W_ * C_ / 2) + k;
        float2* st = (float2*)x1;
        #pragma unroll 1
        for (int it = 0; it < 2; ++it) {
            const int pairA = it * 32 + slot;
            const int pairB = pairA + 16;
            const int pixA = pairA >> 2, gA = pairA & 3;
            const int pixB = pairB >> 2, gB = pairB & 3;
            const float2* xgA = xb2 + gA * (GC_ / 2);
            const float2* xgB = xb2 + gB * (GC_ / 2);
            const uint4* dAp = desc4 + pairA * 9;
            const uint4* dBp = desc4 + pairB * 9;
            float aAx = 0.f, aAy = 0.f, aBx = 0.f, aBy = 0.f;
            #pragma unroll
            for (int p = 0; p < P_; ++p) {
                const uint4 da = dAp[p];
                const uint4 db = dBp[p];
                const float2 vA00 = xgA[(da.x & 0xFFFFu) * 64u];
                const float2 vA01 = xgA[(da.x >> 16) * 64u];
                const float2 vA10 = xgA[(da.y & 0xFFFFu) * 64u];
                const float2 vA11 = xgA[(da.y >> 16) * 64u];
                const float2 vB00 = xgB[(db.x & 0xFFFFu) * 64u];
                const float2 vB01 = xgB[(db.x >> 16) * 64u];
                const float2 vB10 = xgB[(db.y & 0xFFFFu) * 64u];
                const float2 vB11 = xgB[(db.y >> 16) * 64u];
                const float wA00 = h2f(da.z & 0xFFFFu), wA01 = h2f(da.z >> 16);
                const float wA10 = h2f(da.w & 0xFFFFu), wA11 = h2f(da.w >> 16);
                const float wB00 = h2f(db.z & 0xFFFFu), wB01 = h2f(db.z >> 16);
                const float wB10 = h2f(db.w & 0xFFFFu), wB11 = h2f(db.w >> 16);
                aAx = fmaf(wA00, vA00.x, aAx); aAy = fmaf(wA00, vA00.y, aAy);
                aAx = fmaf(wA01, vA01.x, aAx); aAy = fmaf(wA01, vA01.y, aAy);
                aAx = fmaf(wA10, vA10.x, aAx); aAy = fmaf(wA10, vA10.y, aAy);
                aAx = fmaf(wA11, vA11.x, aAx); aAy = fmaf(wA11, vA11.y, aAy);
                aBx = fmaf(wB00, vB00.x, aBx); aBy = fmaf(wB00, vB00.y, aBy);
                aBx = fmaf(wB01, vB01.x, aBx); aBy = fmaf(wB01, vB01.y, aBy);
                aBx = fmaf(wB10, vB10.x, aBx); aBy = fmaf(wB10, vB10.y, aBy);
                aBx = fmaf(wB11, vB11.x, aBx); aBy = fmaf(wB11, vB11.y, aBy);
            }
            st[pixA * (X1S / 2) + gA * (GC_ / 2) + k] = make_float2(aAx, aAy);
            st[pixB * (X1S / 2) + gB * (GC_ / 2) + k] = make_float2(aBx, aBy);
        }
    }
    __syncthreads();
    {
        const int pix = t & 15;
        const int cq  = t >> 4;
        #pragma unroll
        for (int i = 0; i < 8; ++i) {
            const int c = cq * 8 + i;
            out[(((size_t)n * C_ + c) * H_ + h) * W_ + w0 + pix] = x1[pix * X1S + c];
        }
    }
}

extern "C" void kernel_launch(void* const* d_in, const int* in_sizes, int n_in,
                              void* d_out, int out_size, void* d_ws, size_t ws_size,
                              hipStream_t stream) {
    const float* inp  = (const float*)d_in[0];
    const float* xin  = (const float*)d_in[1];
    const float* dww  = (const float*)d_in[2];
    const float* dwb  = (const float*)d_in[3];
    const float* lng  = (const float*)d_in[4];
    const float* lnb  = (const float*)d_in[5];
    const float* offw = (const float*)d_in[6];
    const float* offb = (const float*)d_in[7];
    float* outp = (float*)d_out;

    if (ws_size >= DESC_BYTES) {
        uint4* desc = (uint4*)d_ws;
        dcn_convoffs<<<dim3(1024), dim3(256), 0, stream>>>(
            inp, dww, dwb, lng, lnb, offw, offb, desc);
        dcn_gather<<<dim3(2048), dim3(512), 0, stream>>>(xin, desc, outp);
    } else {
        dcn_fused_mono<<<dim3(N_ * H_ * (W_ / WT)), dim3(256), 0, stream>>>(
            inp, xin, dww, dwb, lng, lnb, offw, offb, outp);
    }
}